// Round 1
// baseline (149.074 us; speedup 1.0000x reference)
//
#include <hip/hip_runtime.h>

// Chamfer distance, pred [B,N,3] fp32, gt [B,M,3] fp32 -> scalar.
// d(p,q) = ||p||^2 + ||q||^2 - 2 p.q. Targets pre-transformed to
// (-2x,-2y,-2z,||q||^2); query ||p||^2 hoisted outside the min.
// Inner loop: 3 FMA + fused min3 per 2 targets => ~3.5 VALU ops/pair.

#define B_SZ   8
#define N_PTS  8192
#define M_PTS  8192

#define BLOCK   256
#define RQ      8      // queries per thread (register-tiled)
#define NT_TILE 256    // targets staged in LDS per block
#define SPLITS  32     // M_PTS / NT_TILE target splits (for occupancy)

// pts: [n,3] -> T: [n] float4 = (-2x,-2y,-2z, x^2+y^2+z^2)
__global__ __launch_bounds__(BLOCK) void chamfer_prep(
    const float* __restrict__ pts, float4* __restrict__ T, int n)
{
    int i = blockIdx.x * BLOCK + threadIdx.x;
    if (i < n) {
        float x = pts[3 * i + 0];
        float y = pts[3 * i + 1];
        float z = pts[3 * i + 2];
        T[i] = make_float4(-2.f * x, -2.f * y, -2.f * z,
                           fmaf(x, x, fmaf(y, y, z * z)));
    }
}

// For each query point, min over a slice of targets of
// dt = qw + qx*px + qy*py + qz*pz  (= ||q||^2 - 2 p.q).
// Final d = max(dt_min + ||p||^2, 0), combined across slices via
// atomicMin on float bits (valid: all stored values are >= 0).
__global__ __launch_bounds__(BLOCK) void chamfer_nn_min(
    const float* __restrict__ qry,       // [B, Nq, 3]
    const float4* __restrict__ tgt,      // [B, Nt] transformed
    unsigned int* __restrict__ minbuf,   // [B*Nq] float bits, init big
    int Nq, int Nt)
{
    __shared__ float4 tile[NT_TILE];
    const int qb = blockIdx.x;   // query block within batch
    const int b  = blockIdx.y;   // batch
    const int s  = blockIdx.z;   // target split
    const int t  = threadIdx.x;

    // stage this split's targets into LDS (NT_TILE == BLOCK: one each)
    tile[t] = tgt[(size_t)b * Nt + (size_t)s * NT_TILE + t];

    // load RQ query points into registers (strided for coalescing)
    const int qbase = qb * (BLOCK * RQ);
    const float* qp = qry + ((size_t)b * Nq + qbase) * 3;
    float px[RQ], py[RQ], pz[RQ], mn[RQ];
#pragma unroll
    for (int k = 0; k < RQ; ++k) {
        int qi = k * BLOCK + t;
        px[k] = qp[3 * qi + 0];
        py[k] = qp[3 * qi + 1];
        pz[k] = qp[3 * qi + 2];
        mn[k] = 3.0e38f;
    }
    __syncthreads();

#pragma unroll 2
    for (int j = 0; j < NT_TILE; j += 2) {
        float4 q0 = tile[j];       // same addr across lanes: broadcast
        float4 q1 = tile[j + 1];
#pragma unroll
        for (int k = 0; k < RQ; ++k) {
            float d0 = fmaf(q0.x, px[k], q0.w);
            d0 = fmaf(q0.y, py[k], d0);
            d0 = fmaf(q0.z, pz[k], d0);
            float d1 = fmaf(q1.x, px[k], q1.w);
            d1 = fmaf(q1.y, py[k], d1);
            d1 = fmaf(q1.z, pz[k], d1);
            mn[k] = fminf(fminf(mn[k], d0), d1);   // hope: v_min3_f32
        }
    }

#pragma unroll
    for (int k = 0; k < RQ; ++k) {
        int qi = qbase + k * BLOCK + t;
        float p2 = fmaf(px[k], px[k], fmaf(py[k], py[k], pz[k] * pz[k]));
        float d  = fmaxf(mn[k] + p2, 0.0f);
        atomicMin(&minbuf[(size_t)b * Nq + qi], __float_as_uint(d));
    }
}

// out = sum(a)*sa + sum(b)*sb  (single block)
__global__ __launch_bounds__(1024) void chamfer_reduce(
    const float* __restrict__ a, int na,
    const float* __restrict__ b, int nb,
    float* __restrict__ out, float sa, float sb)
{
    __shared__ float part[16];
    float s = 0.f;
    const float4* a4 = (const float4*)a;
    for (int i = threadIdx.x; i < na / 4; i += 1024) {
        float4 v = a4[i];
        s += (v.x + v.y + v.z + v.w) * sa;
    }
    const float4* b4 = (const float4*)b;
    for (int i = threadIdx.x; i < nb / 4; i += 1024) {
        float4 v = b4[i];
        s += (v.x + v.y + v.z + v.w) * sb;
    }
    for (int o = 32; o > 0; o >>= 1) s += __shfl_down(s, o, 64);
    int w = threadIdx.x >> 6;
    if ((threadIdx.x & 63) == 0) part[w] = s;
    __syncthreads();
    if (threadIdx.x == 0) {
        float tot = 0.f;
        for (int i = 0; i < 16; ++i) tot += part[i];
        out[0] = tot;
    }
}

extern "C" void kernel_launch(void* const* d_in, const int* in_sizes, int n_in,
                              void* d_out, int out_size, void* d_ws, size_t ws_size,
                              hipStream_t stream) {
    const float* pred = (const float*)d_in[0];   // [B, N, 3]
    const float* gt   = (const float*)d_in[1];   // [B, M, 3]
    float* out = (float*)d_out;

    const int BN = B_SZ * N_PTS;   // 65536
    const int BM = B_SZ * M_PTS;   // 65536

    // workspace layout (bytes):
    //   [0, 1MB)      Tg : transformed gt,   BM float4
    //   [1MB, 2MB)    Tp : transformed pred, BN float4
    //   [2MB, 2.25MB) minP: B*N uint  (pred->gt mins)
    //   [2.25,2.5MB)  minG: B*M uint  (gt->pred mins)
    char* ws = (char*)d_ws;
    float4*       Tg   = (float4*)(ws);
    float4*       Tp   = (float4*)(ws + (size_t)BM * 16);
    unsigned int* minP = (unsigned int*)(ws + (size_t)(BM + BN) * 16);
    unsigned int* minG = minP + BN;

    // init min buffers to 0x7f7f7f7f (~3.39e38 as float, positive, huge)
    hipMemsetAsync(minP, 0x7f, (size_t)(BN + BM) * 4, stream);

    chamfer_prep<<<(BM + BLOCK - 1) / BLOCK, BLOCK, 0, stream>>>(gt, Tg, BM);
    chamfer_prep<<<(BN + BLOCK - 1) / BLOCK, BLOCK, 0, stream>>>(pred, Tp, BN);

    dim3 grid_p(N_PTS / (BLOCK * RQ), B_SZ, SPLITS);
    chamfer_nn_min<<<grid_p, BLOCK, 0, stream>>>(pred, Tg, minP, N_PTS, M_PTS);
    dim3 grid_g(M_PTS / (BLOCK * RQ), B_SZ, SPLITS);
    chamfer_nn_min<<<grid_g, BLOCK, 0, stream>>>(gt, Tp, minG, M_PTS, N_PTS);

    chamfer_reduce<<<1, 1024, 0, stream>>>(
        (const float*)minP, BN, (const float*)minG, BM, out,
        1.0f / (float)BN, 1.0f / (float)BM);
}

// Round 2
// 141.280 us; speedup vs baseline: 1.0552x; 1.0552x over previous
//
#include <hip/hip_runtime.h>

// Chamfer distance, pred [B,N,3] fp32, gt [B,M,3] fp32 -> scalar.
// d(p,q) = ||p||^2 + ||q||^2 - 2 p.q. Targets pre-transformed, PAIR-PACKED:
// per target pair {(-2x0,-2x1,-2y0,-2y1), (-2z0,-2z1,w0,w1)}, w=||q||^2.
// Inner loop per 2 targets per query: 3 v_pk_fma_f32 + 1 v_min3_f32
// = 2 VALU inst/pair (vs 3.5 scalar). Query ||p||^2 hoisted outside min.

typedef float vf2 __attribute__((ext_vector_type(2)));
typedef float vf4 __attribute__((ext_vector_type(4)));

#define B_SZ   8
#define N_PTS  8192
#define M_PTS  8192

#define BLOCK   256
#define RQ      8      // queries per thread (register-tiled)
#define NT_TILE 256    // targets staged in LDS per block
#define SPLITS  32     // target splits (occupancy)
#define RED_GRID 128   // reduce blocks

// pts [n,3] -> T: per pair g: T[2g]=(-2x0,-2x1,-2y0,-2y1), T[2g+1]=(-2z0,-2z1,w0,w1)
// (batches are contiguous and M even, so flat pairing never crosses a batch)
__global__ __launch_bounds__(BLOCK) void chamfer_prep_pk(
    const float* __restrict__ pts, vf4* __restrict__ T, int npairs)
{
    int g = blockIdx.x * BLOCK + threadIdx.x;
    if (g < npairs) {
        const float* p = pts + 6 * (size_t)g;
        float x0 = p[0], y0 = p[1], z0 = p[2];
        float x1 = p[3], y1 = p[4], z1 = p[5];
        float w0 = fmaf(x0, x0, fmaf(y0, y0, z0 * z0));
        float w1 = fmaf(x1, x1, fmaf(y1, y1, z1 * z1));
        vf4 XY = { -2.f * x0, -2.f * x1, -2.f * y0, -2.f * y1 };
        vf4 ZW = { -2.f * z0, -2.f * z1, w0, w1 };
        T[2 * (size_t)g]     = XY;
        T[2 * (size_t)g + 1] = ZW;
    }
}

__global__ __launch_bounds__(BLOCK) void chamfer_nn_min_pk(
    const float* __restrict__ qry,       // [B, Nq, 3] raw
    const vf4* __restrict__ tgt,         // [B, Nt] pair-packed (Nt vf4 per batch)
    unsigned int* __restrict__ minbuf,   // [B*Nq] float bits, init big
    int Nq, int Nt)
{
    __shared__ vf4 tile[NT_TILE];        // NT_TILE/2 pairs x 2 vf4
    const int qb = blockIdx.x;
    const int b  = blockIdx.y;
    const int s  = blockIdx.z;
    const int t  = threadIdx.x;

    tile[t] = tgt[(size_t)b * Nt + (size_t)s * NT_TILE + t];

    const int qbase = qb * (BLOCK * RQ);
    const float* qp = qry + ((size_t)b * Nq + qbase) * 3;
    vf2 Px[RQ], Py[RQ], Pz[RQ];
    float mn[RQ];
#pragma unroll
    for (int k = 0; k < RQ; ++k) {
        int qi = k * BLOCK + t;
        float x = qp[3 * qi + 0];
        float y = qp[3 * qi + 1];
        float z = qp[3 * qi + 2];
        Px[k] = (vf2){x, x}; Py[k] = (vf2){y, y}; Pz[k] = (vf2){z, z};
        mn[k] = 3.0e38f;
    }
    __syncthreads();

#pragma unroll 2
    for (int j = 0; j < NT_TILE; j += 2) {   // 2 targets per step
        vf4 v0 = tile[j];                    // (x0,x1,y0,y1) broadcast
        vf4 v1 = tile[j + 1];                // (z0,z1,w0,w1)
        vf2 X = __builtin_shufflevector(v0, v0, 0, 1);
        vf2 Y = __builtin_shufflevector(v0, v0, 2, 3);
        vf2 Z = __builtin_shufflevector(v1, v1, 0, 1);
        vf2 W = __builtin_shufflevector(v1, v1, 2, 3);
#pragma unroll
        for (int k = 0; k < RQ; ++k) {
            vf2 D;
            asm("v_pk_fma_f32 %0, %1, %2, %3" : "=v"(D) : "v"(X), "v"(Px[k]), "v"(W));
            asm("v_pk_fma_f32 %0, %1, %2, %0" : "+v"(D) : "v"(Y), "v"(Py[k]));
            asm("v_pk_fma_f32 %0, %1, %2, %0" : "+v"(D) : "v"(Z), "v"(Pz[k]));
            float dlo = D.x, dhi = D.y;
            asm("v_min3_f32 %0, %0, %1, %2" : "+v"(mn[k]) : "v"(dlo), "v"(dhi));
        }
    }

#pragma unroll
    for (int k = 0; k < RQ; ++k) {
        int qi = qbase + k * BLOCK + t;
        float px = Px[k].x, py = Py[k].x, pz = Pz[k].x;
        float p2 = fmaf(px, px, fmaf(py, py, pz * pz));
        float d  = fmaxf(mn[k] + p2, 0.0f);
        atomicMin(&minbuf[(size_t)b * Nq + qi], __float_as_uint(d));
    }
}

// out += sum(a)*sa + sum(b)*sb, multi-block, out must be zero-initialized
__global__ __launch_bounds__(BLOCK) void chamfer_reduce_pk(
    const float* __restrict__ a, int na,
    const float* __restrict__ b, int nb,
    float* __restrict__ out, float sa, float sb)
{
    __shared__ float part[BLOCK / 64];
    float s = 0.f;
    int tid = blockIdx.x * BLOCK + threadIdx.x;
    int stride = gridDim.x * BLOCK;
    const float4* a4 = (const float4*)a;
    for (int i = tid; i < na / 4; i += stride) {
        float4 v = a4[i];
        s += (v.x + v.y + v.z + v.w) * sa;
    }
    const float4* b4 = (const float4*)b;
    for (int i = tid; i < nb / 4; i += stride) {
        float4 v = b4[i];
        s += (v.x + v.y + v.z + v.w) * sb;
    }
    for (int o = 32; o > 0; o >>= 1) s += __shfl_down(s, o, 64);
    int w = threadIdx.x >> 6;
    if ((threadIdx.x & 63) == 0) part[w] = s;
    __syncthreads();
    if (threadIdx.x == 0) {
        float tot = 0.f;
#pragma unroll
        for (int i = 0; i < BLOCK / 64; ++i) tot += part[i];
        atomicAdd(out, tot);
    }
}

extern "C" void kernel_launch(void* const* d_in, const int* in_sizes, int n_in,
                              void* d_out, int out_size, void* d_ws, size_t ws_size,
                              hipStream_t stream) {
    const float* pred = (const float*)d_in[0];   // [B, N, 3]
    const float* gt   = (const float*)d_in[1];   // [B, M, 3]
    float* out = (float*)d_out;

    const int BN = B_SZ * N_PTS;   // 65536
    const int BM = B_SZ * M_PTS;   // 65536

    // workspace layout:
    //   Tg : transformed gt,   BM vf4 (1 MB)
    //   Tp : transformed pred, BN vf4 (1 MB)
    //   minP: B*N uint, minG: B*M uint
    char* ws = (char*)d_ws;
    vf4*          Tg   = (vf4*)(ws);
    vf4*          Tp   = (vf4*)(ws + (size_t)BM * 16);
    unsigned int* minP = (unsigned int*)(ws + (size_t)(BM + BN) * 16);
    unsigned int* minG = minP + BN;

    hipMemsetAsync(minP, 0x7f, (size_t)(BN + BM) * 4, stream);  // ~3.39e38
    hipMemsetAsync(out, 0, sizeof(float), stream);              // for atomicAdd

    chamfer_prep_pk<<<(BM / 2 + BLOCK - 1) / BLOCK, BLOCK, 0, stream>>>(gt, Tg, BM / 2);
    chamfer_prep_pk<<<(BN / 2 + BLOCK - 1) / BLOCK, BLOCK, 0, stream>>>(pred, Tp, BN / 2);

    dim3 grid_p(N_PTS / (BLOCK * RQ), B_SZ, SPLITS);
    chamfer_nn_min_pk<<<grid_p, BLOCK, 0, stream>>>(pred, Tg, minP, N_PTS, M_PTS);
    dim3 grid_g(M_PTS / (BLOCK * RQ), B_SZ, SPLITS);
    chamfer_nn_min_pk<<<grid_g, BLOCK, 0, stream>>>(gt, Tp, minG, M_PTS, N_PTS);

    chamfer_reduce_pk<<<RED_GRID, BLOCK, 0, stream>>>(
        (const float*)minP, BN, (const float*)minG, BM, out,
        1.0f / (float)BN, 1.0f / (float)BM);
}